// Round 1
// baseline (1946.350 us; speedup 1.0000x reference)
//
#include <hip/hip_runtime.h>

typedef unsigned short u16;
typedef __bf16 bf16x8 __attribute__((ext_vector_type(8)));
typedef float f32x4 __attribute__((ext_vector_type(4)));

#define NEXP 30
#define INSZ 1024
#define HID 2048
#define NB 8192

// ---------- helpers ----------
__device__ __forceinline__ u16 f2bf(float f) {
    union { float f; unsigned u; } x; x.f = f;
    unsigned r = x.u + 0x7FFFu + ((x.u >> 16) & 1u);   // RNE
    return (u16)(r >> 16);
}

typedef __attribute__((address_space(3))) unsigned int lds_u32;
typedef const __attribute__((address_space(1))) unsigned int glb_u32;
__device__ __forceinline__ void gl2lds16(const void* g, void* l) {
    // async global->LDS, 16B per lane; LDS dest must be wave-uniform base + lane*16
    __builtin_amdgcn_global_load_lds((glb_u32*)g, (lds_u32*)l, 16, 0, 0);
}

struct alignas(16) U16x8 { u16 v[8]; };

// ---------- conversion: x fp32 -> bf16 (same layout) ----------
__global__ __launch_bounds__(256) void conv_x(const float* __restrict__ in,
                                              u16* __restrict__ out) {
    size_t base = ((size_t)blockIdx.x * 256 + threadIdx.x) * 8;
    float4 v0 = *(const float4*)(in + base);
    float4 v1 = *(const float4*)(in + base + 4);
    U16x8 o;
    o.v[0] = f2bf(v0.x); o.v[1] = f2bf(v0.y); o.v[2] = f2bf(v0.z); o.v[3] = f2bf(v0.w);
    o.v[4] = f2bf(v1.x); o.v[5] = f2bf(v1.y); o.v[6] = f2bf(v1.z); o.v[7] = f2bf(v1.w);
    *(U16x8*)(out + base) = o;
}

// ---------- conversion: W1 [E][I][H] fp32 -> Wt [E][H][I] bf16 (tiled transpose) ----------
__global__ __launch_bounds__(256) void conv_w1(const float* __restrict__ W1,
                                               u16* __restrict__ Wt) {
    __shared__ float t[32][33];
    const int e  = blockIdx.z;
    const int h0 = blockIdx.x * 32;
    const int i0 = blockIdx.y * 32;
    const int tx = threadIdx.x, ty = threadIdx.y;   // 32 x 8
    const float* src = W1 + (size_t)e * INSZ * HID;
    u16* dst = Wt + (size_t)e * HID * INSZ;
    #pragma unroll
    for (int j = 0; j < 32; j += 8)
        t[ty + j][tx] = src[(size_t)(i0 + ty + j) * HID + h0 + tx];
    __syncthreads();
    #pragma unroll
    for (int j = 0; j < 32; j += 8)
        dst[(size_t)(h0 + ty + j) * INSZ + i0 + tx] = f2bf(t[tx][ty + j]);
}

// ---------- fused fc1(MFMA bf16) + ReLU + fc2 + sigmoid + mean ----------
// block = 128 batch rows x 1 expert; 4 waves; N-loop 2048 in 128-tiles; K-loop 1024 in 32s
__global__ __launch_bounds__(256) void fused_mlp(
        const u16* __restrict__ Xb,   // [NB][INSZ] bf16
        const u16* __restrict__ Wt,   // [E][HID][INSZ] bf16
        const float* __restrict__ b1, // [E][HID]
        const float* __restrict__ W2, // [E][HID]
        const float* __restrict__ b2, // [E]
        float* __restrict__ out)      // [NB]
{
    __shared__ __attribute__((aligned(16))) u16 As[128 * 32];  // [m][k]
    __shared__ __attribute__((aligned(16))) u16 Bs[128 * 32];  // [n][k]
    __shared__ float rsum[128];

    const int e     = blockIdx.y;
    const int mbase = blockIdx.x * 128;
    const int tid   = threadIdx.x;
    const int wave  = tid >> 6;
    const int lane  = tid & 63;
    const int q     = lane >> 4;       // quad
    const int c     = lane & 15;
    const int wrow  = wave >> 1;       // 0..1  (64-row half)
    const int wcol  = wave & 1;        // 0..1  (64-col half)

    const u16* xbase = Xb + (size_t)mbase * INSZ;
    const u16* wbase = Wt + (size_t)e * HID * INSZ;
    const float* b1e = b1 + e * HID;
    const float* w2e = W2 + e * HID;

    // staging map: thread t, pass s -> row = t/4 + s*64, col = (t%4)*8  (16B per lane)
    const int st_row = tid >> 2;
    const int st_col = (tid & 3) * 8;

    float rowacc[16];
    #pragma unroll
    for (int i = 0; i < 16; i++) rowacc[i] = 0.f;

    for (int n0 = 0; n0 < HID; n0 += 128) {
        f32x4 acc[4][4];
        #pragma unroll
        for (int mi = 0; mi < 4; mi++)
            #pragma unroll
            for (int ni = 0; ni < 4; ni++)
                acc[mi][ni] = f32x4{0.f, 0.f, 0.f, 0.f};

        for (int k0 = 0; k0 < INSZ; k0 += 32) {
            __syncthreads();   // LDS safe to overwrite
            #pragma unroll
            for (int s = 0; s < 2; s++) {
                const u16* g = xbase + (size_t)(st_row + s * 64) * INSZ + k0 + st_col;
                gl2lds16(g, &As[(st_row + s * 64) * 32 + st_col]);
            }
            #pragma unroll
            for (int s = 0; s < 2; s++) {
                const u16* g = wbase + (size_t)(n0 + st_row + s * 64) * INSZ + k0 + st_col;
                gl2lds16(g, &Bs[(st_row + s * 64) * 32 + st_col]);
            }
            asm volatile("s_waitcnt vmcnt(0)" ::: "memory");
            __syncthreads();

            bf16x8 af[4], bfr[4];
            #pragma unroll
            for (int mi = 0; mi < 4; mi++)
                af[mi] = *(const bf16x8*)&As[(wrow * 64 + mi * 16 + c) * 32 + q * 8];
            #pragma unroll
            for (int ni = 0; ni < 4; ni++)
                bfr[ni] = *(const bf16x8*)&Bs[(wcol * 64 + ni * 16 + c) * 32 + q * 8];
            #pragma unroll
            for (int mi = 0; mi < 4; mi++)
                #pragma unroll
                for (int ni = 0; ni < 4; ni++)
                    acc[mi][ni] = __builtin_amdgcn_mfma_f32_16x16x32_bf16(
                        af[mi], bfr[ni], acc[mi][ni], 0, 0, 0);
        }

        // epilogue: +b1, ReLU, *W2, per-row accumulate
        #pragma unroll
        for (int ni = 0; ni < 4; ni++) {
            const int n  = n0 + wcol * 64 + ni * 16 + c;
            const float bb = b1e[n];
            const float ww = w2e[n];
            #pragma unroll
            for (int mi = 0; mi < 4; mi++)
                #pragma unroll
                for (int r = 0; r < 4; r++) {
                    float v = acc[mi][ni][r] + bb;
                    v = fmaxf(v, 0.f);
                    rowacc[mi * 4 + r] = fmaf(v, ww, rowacc[mi * 4 + r]);
                }
        }
    }

    // reduce rowacc across the 16 lanes of each quad (cols), then across waves via LDS
    __syncthreads();
    if (tid < 128) rsum[tid] = 0.f;
    __syncthreads();
    #pragma unroll
    for (int i = 0; i < 16; i++) {
        float v = rowacc[i];
        v += __shfl_xor(v, 1); v += __shfl_xor(v, 2);
        v += __shfl_xor(v, 4); v += __shfl_xor(v, 8);
        if (c == 0) {
            const int mi = i >> 2, r = i & 3;
            atomicAdd(&rsum[wrow * 64 + mi * 16 + q * 4 + r], v);
        }
    }
    __syncthreads();
    if (tid < 128) {
        float z = rsum[tid] + b2[e];
        float s = 1.f / (1.f + __expf(-z));
        atomicAdd(&out[mbase + tid], s * (1.0f / NEXP));
    }
}

// ---------- slow-but-correct fallback (only if ws too small) ----------
__global__ __launch_bounds__(256) void fallback_kernel(
        const float* __restrict__ x, const float* __restrict__ W1,
        const float* __restrict__ b1, const float* __restrict__ W2,
        const float* __restrict__ b2, float* __restrict__ out)
{
    __shared__ float xs[64 * 128];   // 32 KB
    __shared__ float zsum[64];
    const int e  = blockIdx.y;
    const int r0 = blockIdx.x * 64;
    const int tid = threadIdx.x;
    if (tid < 64) zsum[tid] = 0.f;
    const float* W1e = W1 + (size_t)e * INSZ * HID;

    for (int hg = 0; hg < 8; hg++) {
        const int h = hg * 256 + tid;
        float acc[64];
        #pragma unroll
        for (int r = 0; r < 64; r++) acc[r] = 0.f;
        for (int ic = 0; ic < 8; ic++) {
            __syncthreads();
            for (int t = tid; t < 64 * 128; t += 256) {
                int r = t >> 7, i = t & 127;
                xs[t] = x[(size_t)(r0 + r) * INSZ + ic * 128 + i];
            }
            __syncthreads();
            for (int i = 0; i < 128; i++) {
                float wv = W1e[(size_t)(ic * 128 + i) * HID + h];
                #pragma unroll
                for (int r = 0; r < 64; r++)
                    acc[r] = fmaf(xs[r * 128 + i], wv, acc[r]);
            }
        }
        const float bb = b1[e * HID + h];
        const float ww = W2[e * HID + h];
        #pragma unroll
        for (int r = 0; r < 64; r++) {
            float v = fmaxf(acc[r] + bb, 0.f) * ww;
            v += __shfl_xor(v, 1);  v += __shfl_xor(v, 2);  v += __shfl_xor(v, 4);
            v += __shfl_xor(v, 8);  v += __shfl_xor(v, 16); v += __shfl_xor(v, 32);
            if ((tid & 63) == 0) atomicAdd(&zsum[r], v);
        }
    }
    __syncthreads();
    if (tid < 64) {
        float z = zsum[tid] + b2[e];
        atomicAdd(&out[r0 + tid], (1.f / (1.f + __expf(-z))) * (1.0f / NEXP));
    }
}

extern "C" void kernel_launch(void* const* d_in, const int* in_sizes, int n_in,
                              void* d_out, int out_size, void* d_ws, size_t ws_size,
                              hipStream_t stream) {
    const float* x  = (const float*)d_in[0];
    const float* W1 = (const float*)d_in[1];
    const float* b1 = (const float*)d_in[2];
    const float* W2 = (const float*)d_in[3];
    const float* b2 = (const float*)d_in[4];
    float* out = (float*)d_out;

    hipMemsetAsync(out, 0, (size_t)out_size * sizeof(float), stream);

    const size_t xb_bytes = (size_t)NB * INSZ * sizeof(u16);          // 16 MB
    const size_t wt_bytes = (size_t)NEXP * HID * INSZ * sizeof(u16);  // 126 MB
    if (ws_size >= xb_bytes + wt_bytes) {
        u16* Xb = (u16*)d_ws;
        u16* Wt = (u16*)((char*)d_ws + xb_bytes);
        conv_x<<<dim3((NB * INSZ) / 2048), 256, 0, stream>>>(x, Xb);
        conv_w1<<<dim3(HID / 32, INSZ / 32, NEXP), dim3(32, 8), 0, stream>>>(W1, Wt);
        fused_mlp<<<dim3(NB / 128, NEXP), 256, 0, stream>>>(Xb, Wt, b1, W2, b2, out);
    } else {
        fallback_kernel<<<dim3(NB / 64, NEXP), 256, 0, stream>>>(x, W1, b1, W2, b2, out);
    }
}